// Round 1
// baseline (99.298 us; speedup 1.0000x reference)
//
#include <hip/hip_runtime.h>

// WeightedTensorProduct: out[b, seg[k], c] += x1[b,M1[k],c]*x2[b,M2[k],c]*CG[k]*W[l_ind[k],c]
// Structure (M1/M2/l_ind/M_seg) is a deterministic function of L=3 -> replicate
// _build_structure() at compile time so the 478-entry loop fully unrolls with
// static register indexing (no LDS, no gathers, scalar CG loads).

#define LMAX 3
#define MOUT 16          // (L+1)^2
#define CCH 128          // channels
#define NTRI 34
#define NNZ 478

struct Tables {
    int n_tri = 0;
    int nnz = 0;
    int tl[NTRI] = {}, tl1[NTRI] = {}, tl2[NTRI] = {};
    int M1[NNZ] = {}, M2[NNZ] = {}, LI[NNZ] = {};
    int seg_start[MOUT + 1] = {};
};

constexpr Tables build_tables() {
    Tables T{};
    // triples, insertion order == tri_index order in the reference
    for (int l1 = 0; l1 <= LMAX; ++l1) {
        for (int l2 = 0; l2 <= LMAX; ++l2) {
            int lo = l1 - l2; if (lo < 0) lo = -lo;
            int hi = l1 + l2; if (hi > LMAX) hi = LMAX;
            for (int l = lo; l <= hi; ++l) {
                T.tl[T.n_tri] = l; T.tl1[T.n_tri] = l1; T.tl2[T.n_tri] = l2;
                ++T.n_tri;
            }
        }
    }
    // rows sorted by output order Mo (l outer, m inner -> Mo strictly increasing)
    for (int l = 0; l <= LMAX; ++l) {
        for (int m = -l; m <= l; ++m) {
            const int Mo = l * l + l + m;
            T.seg_start[Mo] = T.nnz;
            for (int t = 0; t < T.n_tri; ++t) {
                if (T.tl[t] != l) continue;
                const int l1 = T.tl1[t], l2 = T.tl2[t];
                int lo = (-l1 > m - l2) ? -l1 : m - l2;
                int hi = (l1 < m + l2) ? l1 : m + l2;
                for (int m1 = lo; m1 <= hi; ++m1) {
                    const int m2 = m - m1;
                    T.M1[T.nnz] = l1 * l1 + l1 + m1;
                    T.M2[T.nnz] = l2 * l2 + l2 + m2;
                    T.LI[T.nnz] = t;
                    ++T.nnz;
                }
            }
        }
    }
    T.seg_start[MOUT] = T.nnz;
    return T;
}

constexpr Tables TB = build_tables();
static_assert(TB.nnz == NNZ, "nnz mismatch vs reference _build_structure");
static_assert(TB.n_tri == NTRI, "n_tri mismatch vs reference _build_structure");

__global__ __launch_bounds__(256)
void wtp_kernel(const float* __restrict__ x1, const float* __restrict__ x2,
                const float* __restrict__ w, const float* __restrict__ cg,
                float* __restrict__ out, int B) {
    const int c = threadIdx.x;                              // channel 0..127
    const int b = blockIdx.x * blockDim.y + threadIdx.y;    // batch
    if (b >= B) return;

    const size_t base = (size_t)b * (MOUT * CCH) + c;
    const float* x1b = x1 + base;
    const float* x2b = x2 + base;

    // x1/x2 rows for this (b,c) into registers: coalesced dword loads per wave
    float x1r[MOUT], x2r[MOUT];
#pragma unroll
    for (int m = 0; m < MOUT; ++m) {
        x1r[m] = x1b[(size_t)m * CCH];
        x2r[m] = x2b[(size_t)m * CCH];
    }

    // all 34 per-triple weights for this channel into registers (L2-hot, coalesced)
    float wr[NTRI];
#pragma unroll
    for (int t = 0; t < NTRI; ++t) wr[t] = w[t * CCH + c];

    float* outb = out + base;
#pragma unroll
    for (int mo = 0; mo < MOUT; ++mo) {
        float acc = 0.f;
        const int ks = TB.seg_start[mo];
        const int ke = TB.seg_start[mo + 1];
#pragma unroll
        for (int k = ks; k < ke; ++k) {
            // cg[k] is wave-uniform with compile-time offset -> scalar load
            acc = fmaf(x1r[TB.M1[k]] * x2r[TB.M2[k]], cg[k] * wr[TB.LI[k]], acc);
        }
        outb[(size_t)mo * CCH] = acc;
    }
}

extern "C" void kernel_launch(void* const* d_in, const int* in_sizes, int n_in,
                              void* d_out, int out_size, void* d_ws, size_t ws_size,
                              hipStream_t stream) {
    const float* x1 = (const float*)d_in[0];
    const float* x2 = (const float*)d_in[1];
    const float* w  = (const float*)d_in[2];
    const float* cg = (const float*)d_in[3];
    // d_in[4..7] are the index arrays; structure is compile-time replicated.
    float* out = (float*)d_out;

    const int B = in_sizes[0] / (MOUT * CCH);   // 2048

    dim3 block(CCH, 2, 1);                      // 256 threads: lane = channel
    dim3 grid((B + 1) / 2, 1, 1);
    wtp_kernel<<<grid, block, 0, stream>>>(x1, x2, w, cg, out, B);
}